// Round 1
// baseline (1852.976 us; speedup 1.0000x reference)
//
#include <hip/hip_runtime.h>
#include <math.h>

// Conv2dSelfAttention on MI355X — round 1: fp32 baseline.
// B=16, C=512, H=W=64 (N=4096), M=1024 (2x2 pooled), CB=64, CG=256.
//
// Pipeline:
//   xp   = avgpool2(x)                      [B][512][1024]   (pool commutes with 1x1 conv)
//   theta= conv1x1(x, w_theta)              stored [B][4096][64]
//   phi  = conv1x1(xp, w_phi)               stored [B][1024][64]
//   V    = conv1x1(xp, w_g)                 stored [B][1024][256]
//   attn kernel (per 32 query rows): flash-style online softmax over M chunks of 32,
//     PV accumulate in regs, then fused final conv (w_out, b_out) + gamma*y + x.
//
// Workspace: xp 33.5MB | theta 16.8MB | phi 4.2MB | V 16.8MB = 68MB total.

__global__ __launch_bounds__(256) void pool_kernel(const float* __restrict__ x,
                                                   float* __restrict__ xp) {
    int idx = blockIdx.x * 256 + threadIdx.x;   // B*C*M = 8388608
    int m  = idx & 1023;
    int bc = idx >> 10;                          // b*512 + c
    int mh = m >> 5, mw = m & 31;
    const float* xr = x + (size_t)bc * 4096 + mh * 128 + mw * 2;
    float2 r0 = *reinterpret_cast<const float2*>(xr);
    float2 r1 = *reinterpret_cast<const float2*>(xr + 64);
    xp[idx] = 0.25f * (r0.x + r0.y + r1.x + r1.y);
}

// Generic 1x1 conv as tiled GEMM.
//   in  : [B][512][NL]  (NL contiguous)
//   w   : [O][512]
//   out : [B][NL][O]    (O contiguous)
// Block computes a 64n x 64o tile; O = gridDim.y * 64.
__global__ __launch_bounds__(256) void conv1x1_kernel(const float* __restrict__ in,
                                                      const float* __restrict__ w,
                                                      const float* __restrict__ bias,
                                                      float* __restrict__ out,
                                                      int NL) {
    __shared__ float Xs[16 * 65];   // [cc][n]
    __shared__ float Ws[16 * 65];   // [cc][o]
    const int t  = threadIdx.x;
    const int n0 = blockIdx.x * 64;
    const int o0 = blockIdx.y * 64;
    const int b  = blockIdx.z;
    const int O  = gridDim.y * 64;
    const int tn = t >> 4, to = t & 15;
    const float* inb = in + (size_t)b * 512 * NL;

    const int xc = t >> 4;               // staging: 16 c-rows x 64 n
    const int xn = (t & 15) * 4;
    const int wo = t >> 2;               // staging: 64 o-rows x 16 c
    const int wc4 = (t & 3) * 4;

    float acc[4][4] = {};

    for (int c0 = 0; c0 < 512; c0 += 16) {
        float4 xv4 = *reinterpret_cast<const float4*>(inb + (size_t)(c0 + xc) * NL + n0 + xn);
        Xs[xc * 65 + xn + 0] = xv4.x;
        Xs[xc * 65 + xn + 1] = xv4.y;
        Xs[xc * 65 + xn + 2] = xv4.z;
        Xs[xc * 65 + xn + 3] = xv4.w;
        float4 wv4 = *reinterpret_cast<const float4*>(w + (size_t)(o0 + wo) * 512 + c0 + wc4);
        Ws[(wc4 + 0) * 65 + wo] = wv4.x;
        Ws[(wc4 + 1) * 65 + wo] = wv4.y;
        Ws[(wc4 + 2) * 65 + wo] = wv4.z;
        Ws[(wc4 + 3) * 65 + wo] = wv4.w;
        __syncthreads();
#pragma unroll
        for (int cc = 0; cc < 16; ++cc) {
            float xv[4], wv[4];
#pragma unroll
            for (int a = 0; a < 4; ++a) xv[a] = Xs[cc * 65 + tn + 16 * a];
#pragma unroll
            for (int bb = 0; bb < 4; ++bb) wv[bb] = Ws[cc * 65 + to + 16 * bb];
#pragma unroll
            for (int a = 0; a < 4; ++a)
#pragma unroll
                for (int bb = 0; bb < 4; ++bb) acc[a][bb] += xv[a] * wv[bb];
        }
        __syncthreads();
    }

    float bv[4];
#pragma unroll
    for (int bb = 0; bb < 4; ++bb) bv[bb] = bias[o0 + to + 16 * bb];
#pragma unroll
    for (int a = 0; a < 4; ++a) {
        const size_t row = ((size_t)b * NL + n0 + tn + 16 * a) * O;
#pragma unroll
        for (int bb = 0; bb < 4; ++bb)
            out[row + o0 + to + 16 * bb] = acc[a][bb] + bv[bb];
    }
}

// Fused attention + final conv + residual.
// Grid: (N/32, B). Block: 256 threads.
// theta [B][4096][64], phi [B][1024][64], V [B][1024][256],
// w_out [512][256], out/x [B][512][4096].
__global__ __launch_bounds__(256) void attn_kernel(const float* __restrict__ theta,
                                                   const float* __restrict__ phi,
                                                   const float* __restrict__ vmat,
                                                   const float* __restrict__ w_out,
                                                   const float* __restrict__ b_out,
                                                   const float* __restrict__ gamma,
                                                   const float* __restrict__ x,
                                                   float* __restrict__ out) {
    // Phase layout:   Tt[32][68] | Pp[32][68] | Ss[32][33] | Vs[32][260]  = 13728 floats
    // Epilogue layout: Wt[64][65] (offset 0) | O[32][261] (offset 4160)   (reuses same region)
    __shared__ float lds[13728];
    __shared__ float scl[32];
    float* Tt = lds;              // theta tile
    float* Pp = lds + 2176;       // phi chunk
    float* Ss = lds + 4352;       // scores chunk
    float* Vs = lds + 5408;       // V chunk

    const int t  = threadIdx.x;
    const int b  = blockIdx.y;
    const int n0 = blockIdx.x * 32;

    const int lr  = t >> 3;          // 0..31 (staging row + S-compute row)
    const int lc8 = (t & 7) * 8;     // 0..56

    // load theta tile (32 x 64)
    {
        const float4* src = reinterpret_cast<const float4*>(
            theta + ((size_t)b * 4096 + n0 + lr) * 64 + lc8);
        float4* dst = reinterpret_cast<float4*>(Tt + lr * 68 + lc8);
        dst[0] = src[0];
        dst[1] = src[1];
    }

    const int r_pv = t & 31;
    const int cg0  = (t >> 5) * 32;
    float acc[32] = {};
    float m_run = -INFINITY, l_run = 0.0f;

    for (int mc = 0; mc < 1024; mc += 32) {
        // stage phi chunk (32 x 64)
        {
            const float4* src = reinterpret_cast<const float4*>(
                phi + ((size_t)b * 1024 + mc + lr) * 64 + lc8);
            float4* dst = reinterpret_cast<float4*>(Pp + lr * 68 + lc8);
            dst[0] = src[0];
            dst[1] = src[1];
        }
        // stage V chunk (32 x 256)
        {
            const float4* src = reinterpret_cast<const float4*>(
                vmat + ((size_t)b * 1024 + mc + lr) * 256 + (t & 7) * 32);
            float4* dst = reinterpret_cast<float4*>(Vs + lr * 260 + (t & 7) * 32);
#pragma unroll
            for (int i = 0; i < 8; ++i) dst[i] = src[i];
        }
        __syncthreads();

        // scores: S[r][mm] = dot64(theta_r, phi_mm); each thread does 4 mm
        {
            const float* Tr = Tt + lr * 68;
            const int mmb = t & 7;
#pragma unroll
            for (int q = 0; q < 4; ++q) {
                const int mm = mmb + 8 * q;
                const float* Pr = Pp + mm * 68;
                float dot = 0.0f;
#pragma unroll
                for (int c = 0; c < 64; c += 4) {
                    float4 tv = *reinterpret_cast<const float4*>(Tr + c);
                    float4 pv = *reinterpret_cast<const float4*>(Pr + c);
                    dot += tv.x * pv.x + tv.y * pv.y + tv.z * pv.z + tv.w * pv.w;
                }
                Ss[lr * 33 + mm] = dot;
            }
        }
        __syncthreads();

        // online softmax row ops (wave 0, one lane per row)
        if (t < 32) {
            float* Sr = Ss + t * 33;
            float mx = m_run;
#pragma unroll
            for (int mm = 0; mm < 32; ++mm) mx = fmaxf(mx, Sr[mm]);
            float sc = __expf(m_run - mx);   // first chunk: exp(-inf - finite) = 0
            float sum = 0.0f;
#pragma unroll
            for (int mm = 0; mm < 32; ++mm) {
                float p = __expf(Sr[mm] - mx);
                Sr[mm] = p;
                sum += p;
            }
            l_run = l_run * sc + sum;
            m_run = mx;
            scl[t] = sc;
        }
        __syncthreads();

        // PV accumulate: acc[j] = acc[j]*sc + sum_mm p[r][mm] * V[mm][cg0+j]
        {
            const float sc = scl[r_pv];
#pragma unroll
            for (int j = 0; j < 32; ++j) acc[j] *= sc;
            const float* Sr = Ss + r_pv * 33;
            for (int mm = 0; mm < 32; ++mm) {
                const float p = Sr[mm];
                const float* Vr = Vs + mm * 260 + cg0;
#pragma unroll
                for (int j = 0; j < 32; j += 4) {
                    float4 vv = *reinterpret_cast<const float4*>(Vr + j);
                    acc[j + 0] += p * vv.x;
                    acc[j + 1] += p * vv.y;
                    acc[j + 2] += p * vv.z;
                    acc[j + 3] += p * vv.w;
                }
            }
        }
        __syncthreads();
    }

    if (t < 32) scl[t] = 1.0f / l_run;
    __syncthreads();

    // write normalized out2 tile O[32][256] (pad 261, conflict-free reads)
    float* O = lds + 4160;
    {
        const float li = scl[r_pv];
#pragma unroll
        for (int j = 0; j < 32; ++j) O[r_pv * 261 + cg0 + j] = acc[j] * li;
    }
    __syncthreads();

    // fused final conv: y[c][n] = sum_k O[n][k]*w_out[c][k] + b_out[c]; out = gamma*y + x
    float* Wt = lds;   // [64 k][65]
    const int tn = t & 15, tc = t >> 4;
    const float gamma0 = gamma[0];

    for (int c0 = 0; c0 < 512; c0 += 64) {
        float acc2[2][4] = {};
        for (int k0 = 0; k0 < 256; k0 += 64) {
            // stage w_out^T chunk [64k][64c]
            {
                const int wc = t >> 2;
                const int wk = (t & 3) * 16;
                const float4* src = reinterpret_cast<const float4*>(
                    w_out + (size_t)(c0 + wc) * 256 + k0 + wk);
#pragma unroll
                for (int i = 0; i < 4; ++i) {
                    float4 v = src[i];
                    Wt[(wk + 4 * i + 0) * 65 + wc] = v.x;
                    Wt[(wk + 4 * i + 1) * 65 + wc] = v.y;
                    Wt[(wk + 4 * i + 2) * 65 + wc] = v.z;
                    Wt[(wk + 4 * i + 3) * 65 + wc] = v.w;
                }
            }
            __syncthreads();
#pragma unroll 8
            for (int kk = 0; kk < 64; ++kk) {
                const float xv0 = O[tn * 261 + k0 + kk];
                const float xv1 = O[(tn + 16) * 261 + k0 + kk];
#pragma unroll
                for (int bb = 0; bb < 4; ++bb) {
                    const float wv = Wt[kk * 65 + tc + 16 * bb];
                    acc2[0][bb] += xv0 * wv;
                    acc2[1][bb] += xv1 * wv;
                }
            }
            __syncthreads();
        }
#pragma unroll
        for (int bb = 0; bb < 4; ++bb) {
            const int c = c0 + tc + 16 * bb;
            const float bo = b_out[c];
#pragma unroll
            for (int a = 0; a < 2; ++a) {
                const int n = n0 + tn + 16 * a;
                const size_t idx = ((size_t)b * 512 + c) * 4096 + n;
                out[idx] = gamma0 * (acc2[a][bb] + bo) + x[idx];
            }
        }
    }
}

extern "C" void kernel_launch(void* const* d_in, const int* in_sizes, int n_in,
                              void* d_out, int out_size, void* d_ws, size_t ws_size,
                              hipStream_t stream) {
    (void)in_sizes; (void)n_in; (void)out_size; (void)ws_size;
    const float* x       = (const float*)d_in[0];
    const float* w_theta = (const float*)d_in[1];
    const float* b_theta = (const float*)d_in[2];
    const float* w_phi   = (const float*)d_in[3];
    const float* b_phi   = (const float*)d_in[4];
    const float* w_g     = (const float*)d_in[5];
    const float* b_g     = (const float*)d_in[6];
    const float* w_out   = (const float*)d_in[7];
    const float* b_out   = (const float*)d_in[8];
    const float* gamma   = (const float*)d_in[9];
    float* out = (float*)d_out;

    char* ws = (char*)d_ws;
    float* xp    = (float*)(ws);                 // 16*512*1024*4 = 33554432 B
    float* theta = (float*)(ws + 33554432);      // 16*4096*64*4  = 16777216 B
    float* phi   = (float*)(ws + 50331648);      // 16*1024*64*4  =  4194304 B
    float* vmat  = (float*)(ws + 54525952);      // 16*1024*256*4 = 16777216 B  (end 71303168)

    pool_kernel<<<32768, 256, 0, stream>>>(x, xp);
    conv1x1_kernel<<<dim3(64, 1, 16), 256, 0, stream>>>(x, w_theta, b_theta, theta, 4096);
    conv1x1_kernel<<<dim3(16, 1, 16), 256, 0, stream>>>(xp, w_phi, b_phi, phi, 1024);
    conv1x1_kernel<<<dim3(16, 4, 16), 256, 0, stream>>>(xp, w_g, b_g, vmat, 1024);
    attn_kernel<<<dim3(128, 16), 256, 0, stream>>>(theta, phi, vmat, w_out, b_out, gamma, x, out);
}

// Round 2
// 310.925 us; speedup vs baseline: 5.9596x; 5.9596x over previous
//
#include <hip/hip_runtime.h>
#include <math.h>

// Conv2dSelfAttention MI355X — round 2: full bf16 MFMA pipeline.
// B=16, C=512, N=4096, M=1024, CB=64, CG=256.
//
// ws layout (53MB): xT_scratch(4 batches) | xpT | theta_b | phi_b | vt_b | w's
// Pipeline: cvt weights -> per-4-batch {transpose+pool, theta conv} ->
//           phi conv, g conv (transposed out) -> fused attn+outconv+residual.

typedef unsigned short u16;
typedef short bf16x8 __attribute__((ext_vector_type(8)));
typedef float f32x16 __attribute__((ext_vector_type(16)));
typedef u16 u16x8 __attribute__((ext_vector_type(8)));
typedef u16 u16x4 __attribute__((ext_vector_type(4)));
typedef int i32x4 __attribute__((ext_vector_type(4)));

#define MFMA32 __builtin_amdgcn_mfma_f32_32x32x16_bf16
#define B_  16
#define C_  512
#define N_  4096
#define M_  1024

__device__ __forceinline__ u16 f2b(float f) {            // fp32 -> bf16 RNE
  unsigned u = __float_as_uint(f);
  return (u16)((u + 0x7FFFu + ((u >> 16) & 1u)) >> 16);
}
__device__ __forceinline__ unsigned pk2(float lo, float hi_) {
  return ((unsigned)f2b(hi_) << 16) | (unsigned)f2b(lo);
}
__device__ __forceinline__ void swap32(unsigned &a, unsigned &b) {
  // a'[l<32]=a[l]; a'[l>=32]=b[l-32]; b'[l<32]=a[l+32]; b'[l>=32]=b[l]
  unsigned sa = (unsigned)__shfl_xor((int)a, 32, 64);
  unsigned sb = (unsigned)__shfl_xor((int)b, 32, 64);
  bool hi = (threadIdx.x & 32) != 0;
  unsigned na = hi ? sb : a;
  unsigned nb = hi ? b : sa;
  a = na; b = nb;
}
__device__ __forceinline__ void async_cp16(u16* lds, const u16* g) {
  __builtin_amdgcn_global_load_lds(
      (const __attribute__((address_space(1))) unsigned int*)g,
      (__attribute__((address_space(3))) unsigned int*)lds, 16, 0, 0);
}
__device__ __forceinline__ f32x16 fz16() {
  f32x16 z;
#pragma unroll
  for (int i = 0; i < 16; ++i) z[i] = 0.0f;
  return z;
}

// ---------------- weight fp32 -> bf16 ----------------
__global__ __launch_bounds__(256) void cvt_kernel(const float* __restrict__ s,
                                                  u16* __restrict__ d, int n4) {
  int i = blockIdx.x * 256 + threadIdx.x;
  if (i < n4) {
    float4 v = *(const float4*)(s + 4 * (size_t)i);
    u16x4 o = {f2b(v.x), f2b(v.y), f2b(v.z), f2b(v.w)};
    *(u16x4*)(d + 4 * (size_t)i) = o;
  }
}

// ---------------- transpose + pool: x[c][n] -> xT[n][c] bf16, xpT[m][c] bf16 ----------------
__global__ __launch_bounds__(256) void transpose_kernel(const float* __restrict__ x,
                                                        u16* __restrict__ xT,
                                                        u16* __restrict__ xpT,
                                                        int batch0) {
  __shared__ float Ls[64 * 132];
  const int t = threadIdx.x;
  const int nb = blockIdx.x;          // n-chunk of 128 (= 2 h-rows), h0 = 2*nb
  const int cb = blockIdx.y;          // c-chunk of 64
  const int z = blockIdx.z;           // local batch
  const int bg = batch0 + z;
  const int n0 = nb * 128, c0 = cb * 64;

  {
    const int c = t >> 2;
    const float* xr = x + ((size_t)(bg * C_ + c0 + c) * N_ + n0);
#pragma unroll
    for (int i = 0; i < 8; ++i) {
      int col4 = (t & 3) + 4 * i;
      float4 v = *(const float4*)(xr + col4 * 4);
      *(float4*)(&Ls[c * 132 + col4 * 4]) = v;
    }
  }
  __syncthreads();
  {  // xT write: n = t>>1, c-half = (t&1)*32
    const int n = t >> 1;
    const int ch = (t & 1) * 32;
    u16 tmp[32];
#pragma unroll
    for (int j = 0; j < 32; ++j) tmp[j] = f2b(Ls[(ch + j) * 132 + n]);
    u16* dst = xT + ((size_t)(z * N_ + n0 + n) * C_ + c0 + ch);
#pragma unroll
    for (int s = 0; s < 4; ++s) *(u16x8*)(dst + s * 8) = *(u16x8*)(&tmp[s * 8]);
  }
  {  // pool: mw = t&31, c8 = (t>>5)*8 ; m = nb*32 + mw
    const int mw = t & 31;
    const int c8 = (t >> 5) * 8;
    u16 tmp[8];
#pragma unroll
    for (int k = 0; k < 8; ++k) {
      const float* lr = &Ls[(c8 + k) * 132 + 2 * mw];
      tmp[k] = f2b(0.25f * (lr[0] + lr[1] + lr[64] + lr[65]));
    }
    u16* dst = xpT + ((size_t)(bg * M_ + nb * 32 + mw) * C_ + c0 + c8);
    *(u16x8*)dst = *(u16x8*)tmp;
  }
}

// ---------------- conv (theta/phi): D[n][o] = src[n][c] @ w[o][c]^T, o=64 ----------------
// src: bf16 [z][NL][512] (pass-local), out: bf16 [batch0+z][NL][64]
__global__ __launch_bounds__(256) void convA_kernel(const u16* __restrict__ src,
                                                    const u16* __restrict__ w_b,
                                                    const float* __restrict__ bias,
                                                    u16* __restrict__ outp,
                                                    int NL, int batch0) {
  const int t = threadIdx.x;
  const int w = t >> 6, l = t & 63, lo = l & 31, hi = l >> 5;
  const int z = blockIdx.z, bg = batch0 + z;
  const int n0 = blockIdx.x * 128;

  f32x16 acc0 = fz16(), acc1 = fz16();
  const u16* ap = src + ((size_t)z * NL + n0 + 32 * w + lo) * C_ + 8 * hi;
  const u16* bp = w_b + (size_t)lo * C_ + 8 * hi;
#pragma unroll 2
  for (int kc = 0; kc < 512; kc += 64) {
#pragma unroll
    for (int kh = 0; kh < 4; ++kh) {
      bf16x8 af = *(const bf16x8*)(ap + kc + kh * 16);
      bf16x8 b0 = *(const bf16x8*)(bp + kc + kh * 16);
      bf16x8 b1 = *(const bf16x8*)(bp + 32 * C_ + kc + kh * 16);
      acc0 = MFMA32(af, b0, acc0, 0, 0, 0);
      acc1 = MFMA32(af, b1, acc1, 0, 0, 0);
    }
  }
  float bv0 = bias[lo], bv1 = bias[32 + lo];
#pragma unroll
  for (int r = 0; r < 16; ++r) {
    int rr_ = (r & 3) + 8 * (r >> 2) + 4 * hi;
    size_t row = ((size_t)bg * NL + n0 + 32 * w + rr_) * 64;
    outp[row + lo] = f2b(acc0[r] + bv0);
    outp[row + 32 + lo] = f2b(acc1[r] + bv1);
  }
}

// ---------------- conv g (transposed out): vt[o][m] = w_g[o][c] @ xpT[m][c]^T ----------------
__global__ __launch_bounds__(256) void convG_kernel(const u16* __restrict__ xpT,
                                                    const u16* __restrict__ wg_b,
                                                    const float* __restrict__ bias,
                                                    u16* __restrict__ vt) {
  const int t = threadIdx.x;
  const int w = t >> 6, l = t & 63, lo = l & 31, hi = l >> 5;
  const int b = blockIdx.z;
  const int m0 = blockIdx.x * 32;

  f32x16 acc0 = fz16(), acc1 = fz16();
  const u16* bp = xpT + ((size_t)(b * M_) + m0 + lo) * C_ + 8 * hi;
  const u16* ap = wg_b + (size_t)(w * 64 + lo) * C_ + 8 * hi;
#pragma unroll 2
  for (int kc = 0; kc < 512; kc += 64) {
#pragma unroll
    for (int kh = 0; kh < 4; ++kh) {
      bf16x8 bfr = *(const bf16x8*)(bp + kc + kh * 16);
      bf16x8 a0 = *(const bf16x8*)(ap + kc + kh * 16);
      bf16x8 a1 = *(const bf16x8*)(ap + (size_t)32 * C_ + kc + kh * 16);
      acc0 = MFMA32(a0, bfr, acc0, 0, 0, 0);
      acc1 = MFMA32(a1, bfr, acc1, 0, 0, 0);
    }
  }
#pragma unroll
  for (int r = 0; r < 16; ++r) {
    int rr_ = (r & 3) + 8 * (r >> 2) + 4 * hi;
    int o0 = w * 64 + rr_;
    vt[((size_t)(b * 256 + o0)) * M_ + m0 + lo] = f2b(acc0[r] + bias[o0]);
    vt[((size_t)(b * 256 + o0 + 32)) * M_ + m0 + lo] = f2b(acc1[r] + bias[o0 + 32]);
  }
}

// ---------------- fused attention + out-conv + residual ----------------
// grid (32, 16): 128 q-rows per block, 4 waves x 32 q. chunks of 64 m.
// theta_b [B][N][64], phi_b [B][M][64], vt_b [B][256][M], wout_b [512][256]
__global__ __launch_bounds__(256, 2) void attn_kernel(const u16* __restrict__ theta_b,
                                                      const u16* __restrict__ phi_b,
                                                      const u16* __restrict__ vt_b,
                                                      const u16* __restrict__ wout_b,
                                                      const float* __restrict__ b_out,
                                                      const float* __restrict__ gamma,
                                                      const float* __restrict__ x,
                                                      float* __restrict__ out) {
  __shared__ u16 smem[32768];  // 64KB: Vs[2][256][64] ; epilogue Os[128][256]

  const int t = threadIdx.x;
  const int w = t >> 6;
  const int l = t & 63;
  const int lo = l & 31;
  const int hi = l >> 5;
  const int b = blockIdx.y;
  const int n0 = blockIdx.x * 128;
  const int qw = n0 + 32 * w;

  int rr[16];
#pragma unroll
  for (int r = 0; r < 16; ++r) rr[r] = (r & 3) + 8 * (r >> 2) + 4 * hi;

  // theta B-frags (col=q=lo, k=c), K=64 -> 4 frags
  bf16x8 thB[4];
  {
    const u16* tp = theta_b + ((size_t)(b * N_ + qw + lo) * 64 + 8 * hi);
#pragma unroll
    for (int kh = 0; kh < 4; ++kh) thB[kh] = *(const bf16x8*)(tp + kh * 16);
  }

  f32x16 acc[8];
#pragma unroll
  for (int ct = 0; ct < 8; ++ct) acc[ct] = fz16();
  float m_run = 0.0f, l_run = 0.0f;

  // V staging: LDS linear, global source pre-swizzled (blk ^= cg&7)
  const int srow = l >> 3;
  const int sswz = (l & 7) ^ srow;
  auto stage = [&](int buf, int mc) {
    const u16* gb = vt_b + ((size_t)(b * 256 + w * 64 + srow) * M_ + mc + sswz * 8);
#pragma unroll
    for (int i = 0; i < 8; ++i)
      async_cp16(&smem[buf * 16384 + (w * 8 + i) * 512], gb + (size_t)i * 8 * M_);
  };

  stage(0, 0);
  __syncthreads();

  for (int ic = 0; ic < 16; ++ic) {
    const int mc = ic * 64;
    const int cur = ic & 1;
    if (ic < 15) stage(cur ^ 1, mc + 64);

    // QK^T swapped: S^T[m][q] tiles (m lane-spread, q = qw+lo per lane)
    f32x16 S[2];
#pragma unroll
    for (int mt = 0; mt < 2; ++mt) {
      S[mt] = fz16();
      const u16* pp = phi_b + ((size_t)(b * M_ + mc + 32 * mt + lo) * 64 + 8 * hi);
#pragma unroll
      for (int kh = 0; kh < 4; ++kh) {
        bf16x8 pa = *(const bf16x8*)(pp + kh * 16);
        S[mt] = MFMA32(pa, thB[kh], S[mt], 0, 0, 0);
      }
    }

    // online softmax, reduction over m is in-lane + hi-partner
    float mx = S[0][0];
#pragma unroll
    for (int i = 1; i < 16; ++i) mx = fmaxf(mx, S[0][i]);
#pragma unroll
    for (int i = 0; i < 16; ++i) mx = fmaxf(mx, S[1][i]);
    mx = fmaxf(mx, __shfl_xor(mx, 32, 64));

    if (__any(mx > m_run + 8.0f)) {  // defer-max (T13)
      float newM = fmaxf(m_run, mx);
      float sc = __expf(m_run - newM);
      m_run = newM;
      l_run *= sc;
#pragma unroll
      for (int r = 0; r < 16; ++r) {
        float scr = __shfl(sc, rr[r], 64);
#pragma unroll
        for (int ct = 0; ct < 8; ++ct) acc[ct][r] *= scr;
      }
    }

    float rsum = 0.0f;
#pragma unroll
    for (int mt = 0; mt < 2; ++mt)
#pragma unroll
      for (int i = 0; i < 16; ++i) {
        float p = __expf(S[mt][i] - m_run);
        S[mt][i] = p;
        rsum += p;
      }
    rsum += __shfl_xor(rsum, 32, 64);
    l_run += rsum;

    // P -> bf16 A-frags in-register (pack + lane32 swap)
    bf16x8 Pf[4];
#pragma unroll
    for (int mt = 0; mt < 2; ++mt)
#pragma unroll
      for (int s = 0; s < 2; ++s) {
        unsigned a0 = pk2(S[mt][8 * s + 0], S[mt][8 * s + 1]);
        unsigned a1 = pk2(S[mt][8 * s + 2], S[mt][8 * s + 3]);
        unsigned a2 = pk2(S[mt][8 * s + 4], S[mt][8 * s + 5]);
        unsigned a3 = pk2(S[mt][8 * s + 6], S[mt][8 * s + 7]);
        swap32(a0, a2);
        swap32(a1, a3);
        i32x4 wv = {(int)a0, (int)a1, (int)a2, (int)a3};
        Pf[mt * 2 + s] = __builtin_bit_cast(bf16x8, wv);
      }

    // PV: acc[ct] += P @ V   (B-frags from swizzled LDS)
    const u16* vbase = &smem[cur * 16384];
#pragma unroll
    for (int ct = 0; ct < 8; ++ct) {
      bf16x8 vf[4];
#pragma unroll
      for (int kh = 0; kh < 4; ++kh) {
        int blk = (2 * kh + hi) ^ (lo & 7);
        vf[kh] = *(const bf16x8*)(vbase + (32 * ct + lo) * 64 + blk * 8);
      }
#pragma unroll
      for (int kh = 0; kh < 4; ++kh)
        acc[ct] = MFMA32(Pf[kh], vf[kh], acc[ct], 0, 0, 0);
    }
    __syncthreads();
  }

  __syncthreads();  // all PV reads done before Os overwrites smem

  float linv = 1.0f / l_run;
  float linv_r[16];
#pragma unroll
  for (int r = 0; r < 16; ++r) linv_r[r] = __shfl(linv, rr[r], 64);

  // write normalized O tile to LDS [128 q][256 cg], XOR-swizzled rows
#pragma unroll
  for (int ct = 0; ct < 8; ++ct)
#pragma unroll
    for (int r = 0; r < 16; ++r) {
      int q = 32 * w + rr[r];
      int blk = (4 * ct + (lo >> 3)) ^ (rr[r] & 7);
      smem[q * 256 + blk * 8 + (lo & 7)] = f2b(acc[ct][r] * linv_r[r]);
    }
  // wave reads only its own 32 rows -> no barrier needed

  bf16x8 Bf[16];
#pragma unroll
  for (int kh = 0; kh < 16; ++kh) {
    int blk = (2 * kh + hi) ^ (lo & 7);
    Bf[kh] = *(const bf16x8*)(&smem[(32 * w + lo) * 256 + blk * 8]);
  }

  const float gamma0 = gamma[0];
#pragma unroll 2
  for (int ct = 0; ct < 16; ++ct) {
    f32x16 facc = fz16();
    const u16* wp = wout_b + (size_t)(32 * ct + lo) * 256 + 8 * hi;
#pragma unroll
    for (int kh = 0; kh < 16; ++kh) {
      bf16x8 af = *(const bf16x8*)(wp + kh * 16);
      facc = MFMA32(af, Bf[kh], facc, 0, 0, 0);
    }
#pragma unroll
    for (int r = 0; r < 16; ++r) {
      int c = 32 * ct + rr[r];
      size_t idx = ((size_t)(b * C_ + c)) * N_ + n0 + 32 * w + lo;
      out[idx] = gamma0 * (facc[r] + b_out[c]) + x[idx];
    }
  }
}

extern "C" void kernel_launch(void* const* d_in, const int* in_sizes, int n_in,
                              void* d_out, int out_size, void* d_ws, size_t ws_size,
                              hipStream_t stream) {
  (void)in_sizes; (void)n_in; (void)out_size; (void)ws_size;
  const float* x       = (const float*)d_in[0];
  const float* w_theta = (const float*)d_in[1];
  const float* b_theta = (const float*)d_in[2];
  const float* w_phi   = (const float*)d_in[3];
  const float* b_phi   = (const float*)d_in[4];
  const float* w_g     = (const float*)d_in[5];
  const float* b_g     = (const float*)d_in[6];
  const float* w_out   = (const float*)d_in[7];
  const float* b_out   = (const float*)d_in[8];
  const float* gamma   = (const float*)d_in[9];
  float* out = (float*)d_out;

  char* ws = (char*)d_ws;
  u16* xT  = (u16*)(ws);               // 4*4096*512*2  = 16,777,216
  u16* xpT = (u16*)(ws + 16777216);    // 16*1024*512*2 = 16,777,216
  u16* th  = (u16*)(ws + 33554432);    // 16*4096*64*2  =  8,388,608
  u16* ph  = (u16*)(ws + 41943040);    // 16*1024*64*2  =  2,097,152
  u16* vt  = (u16*)(ws + 44040192);    // 16*256*1024*2 =  8,388,608
  u16* wth = (u16*)(ws + 52428800);    // 65,536
  u16* wph = (u16*)(ws + 52494336);    // 65,536
  u16* wg  = (u16*)(ws + 52559872);    // 262,144
  u16* wo  = (u16*)(ws + 52822016);    // 262,144  (end 53,084,160)

  cvt_kernel<<<32, 256, 0, stream>>>(w_theta, wth, 8192);
  cvt_kernel<<<32, 256, 0, stream>>>(w_phi, wph, 8192);
  cvt_kernel<<<128, 256, 0, stream>>>(w_g, wg, 32768);
  cvt_kernel<<<128, 256, 0, stream>>>(w_out, wo, 32768);

  for (int p = 0; p < 4; ++p) {
    transpose_kernel<<<dim3(32, 8, 4), 256, 0, stream>>>(x, xT, xpT, 4 * p);
    convA_kernel<<<dim3(32, 1, 4), 256, 0, stream>>>(xT, wth, b_theta, th, 4096, 4 * p);
  }
  convA_kernel<<<dim3(8, 1, 16), 256, 0, stream>>>(xpT, wph, b_phi, ph, 1024, 0);
  convG_kernel<<<dim3(32, 1, 16), 256, 0, stream>>>(xpT, wg, b_g, vt);
  attn_kernel<<<dim3(32, 16), 256, 0, stream>>>(th, ph, vt, wo, b_out, gamma, x, out);
}

// Round 3
// 245.375 us; speedup vs baseline: 7.5516x; 1.2671x over previous
//
#include <hip/hip_runtime.h>
#include <math.h>

// Conv2dSelfAttention MI355X — round 3: fused prep + counted-wait attn pipeline.
// B=16, C=512, N=4096, M=1024, CB=64, CG=256.

typedef unsigned short u16;
typedef short bf16x8 __attribute__((ext_vector_type(8)));
typedef float f32x16 __attribute__((ext_vector_type(16)));
typedef u16 u16x4 __attribute__((ext_vector_type(4)));
typedef int i32x4 __attribute__((ext_vector_type(4)));

#define MFMA32 __builtin_amdgcn_mfma_f32_32x32x16_bf16
#define B_ 16
#define C_ 512
#define N_ 4096
#define M_ 1024
#define LOG2E 1.44269504088896f

__device__ __forceinline__ u16 f2b(float f) {  // fp32 -> bf16 RNE
  unsigned u = __float_as_uint(f);
  return (u16)((u + 0x7FFFu + ((u >> 16) & 1u)) >> 16);
}
__device__ __forceinline__ unsigned cvtpk(float a, float b) {  // lo=a, hi=b
  unsigned r;
  asm("v_cvt_pk_bf16_f32 %0, %1, %2" : "=v"(r) : "v"(a), "v"(b));
  return r;
}
__device__ __forceinline__ void permswap(unsigned &a, unsigned &b) {
  // exchange a's upper 32 lanes with b's lower 32 lanes
  asm("v_permlane32_swap_b32 %0, %1" : "+v"(a), "+v"(b));
}
__device__ __forceinline__ float exp2v(float a) {
  float r;
  asm("v_exp_f32 %0, %1" : "=v"(r) : "v"(a));
  return r;
}
__device__ __forceinline__ void barrier_raw() {
  asm volatile("" ::: "memory");
  __builtin_amdgcn_s_barrier();
  asm volatile("" ::: "memory");
}
__device__ __forceinline__ void async_cp16(u16* lds, const u16* g) {
  __builtin_amdgcn_global_load_lds(
      (const __attribute__((address_space(1))) unsigned int*)g,
      (__attribute__((address_space(3))) unsigned int*)lds, 16, 0, 0);
}
__device__ __forceinline__ f32x16 fz16() {
  f32x16 z;
#pragma unroll
  for (int i = 0; i < 16; ++i) z[i] = 0.0f;
  return z;
}

// ---------------- weight fp32 -> bf16 (optional scale for exp2-domain) ----------------
__global__ __launch_bounds__(256) void cvt_kernel(const float* __restrict__ s,
                                                  u16* __restrict__ d, int n4,
                                                  float scale) {
  int i = blockIdx.x * 256 + threadIdx.x;
  if (i < n4) {
    float4 v = *(const float4*)(s + 4 * (size_t)i);
    u16x4 o = {f2b(v.x * scale), f2b(v.y * scale), f2b(v.z * scale), f2b(v.w * scale)};
    *(u16x4*)(d + 4 * (size_t)i) = o;
  }
}

// ---------------- fused prep: transpose + pool + theta/phi/g convs ----------------
// grid (32 nb, 16 b), 256 thr. Block owns n-rows n0..n0+127 (2 h-rows) and pooled
// m-rows m0..m0+31. Loops c-chunks of 64, accumulating all three convs.
// th [B][N][64] (log2e-scaled), ph [B][M][64], vt [B][256][M].
__global__ __launch_bounds__(256) void prep_kernel(
    const float* __restrict__ x, const u16* __restrict__ wth,
    const u16* __restrict__ wph, const u16* __restrict__ wg,
    const float* __restrict__ bth, const float* __restrict__ bph,
    const float* __restrict__ bg, u16* __restrict__ th, u16* __restrict__ ph,
    u16* __restrict__ vt) {
  __shared__ u16 xb[128 * 68];   // [n][c] bf16 tile
  __shared__ u16 xpt[32 * 68];   // [m][c] pooled bf16 tile
  const int t = threadIdx.x;
  const int w = t >> 6, l = t & 63, lo = l & 31, hi = l >> 5;
  const int nb = blockIdx.x, b = blockIdx.y;
  const int n0 = nb * 128, m0 = nb * 32;
  const int sc = t >> 2, sg = t & 3;  // staging: c-row, col-group of 32

  f32x16 a_th0 = fz16(), a_th1 = fz16(), a_g0 = fz16(), a_g1 = fz16(), a_ph = fz16();

  for (int c0 = 0; c0 < 512; c0 += 64) {
    float v[32];
    const float* xr = x + ((size_t)(b * C_ + c0 + sc)) * N_ + n0 + sg * 32;
#pragma unroll
    for (int i = 0; i < 8; ++i) {
      float4 f = *(const float4*)(xr + 4 * i);
      v[4 * i] = f.x; v[4 * i + 1] = f.y; v[4 * i + 2] = f.z; v[4 * i + 3] = f.w;
    }
    if (c0) __syncthreads();  // prev MFMA phase reads done
    // transpose write (staggered start to spread banks)
#pragma unroll
    for (int jj = 0; jj < 32; ++jj) {
      int j = (jj + 8 * sg) & 31;
      xb[(sg * 32 + j) * 68 + sc] = f2b(v[j]);
    }
    // 2x2 pool: pair cols in-lane, pair h-rows via lane^2 (sg^2)
    float p[16];
#pragma unroll
    for (int j = 0; j < 16; ++j) p[j] = v[2 * j] + v[2 * j + 1];
#pragma unroll
    for (int j = 0; j < 16; ++j) p[j] += __shfl_xor(p[j], 2, 64);
    if (sg < 2) {
#pragma unroll
      for (int j = 0; j < 16; ++j)
        xpt[(sg * 16 + j) * 68 + sc] = f2b(0.25f * p[j]);
    }
    __syncthreads();

    // MFMA phase: theta (A=xb rows n), phi (A=xpt rows m), g (A=wg rows cg, B=xpt cols m)
    const u16* xbw = &xb[(32 * w + lo) * 68 + hi * 8];
    const u16* xpw = &xpt[lo * 68 + hi * 8];
    const u16* wthp = wth + (size_t)lo * C_ + c0 + hi * 8;
    const u16* wphp = wph + (size_t)(32 * w + lo) * C_ + c0 + hi * 8;
    const u16* wgp = wg + (size_t)(64 * w + lo) * C_ + c0 + hi * 8;
#pragma unroll
    for (int kh = 0; kh < 4; ++kh) {
      bf16x8 xa = *(const bf16x8*)(xbw + kh * 16);
      bf16x8 xp8 = *(const bf16x8*)(xpw + kh * 16);
      bf16x8 w0 = *(const bf16x8*)(wthp + kh * 16);
      bf16x8 w1 = *(const bf16x8*)(wthp + (size_t)32 * C_ + kh * 16);
      a_th0 = MFMA32(xa, w0, a_th0, 0, 0, 0);
      a_th1 = MFMA32(xa, w1, a_th1, 0, 0, 0);
      bf16x8 g0 = *(const bf16x8*)(wgp + kh * 16);
      bf16x8 g1 = *(const bf16x8*)(wgp + (size_t)32 * C_ + kh * 16);
      a_g0 = MFMA32(g0, xp8, a_g0, 0, 0, 0);
      a_g1 = MFMA32(g1, xp8, a_g1, 0, 0, 0);
      if (w < 2) {
        bf16x8 wp = *(const bf16x8*)(wphp + kh * 16);
        a_ph = MFMA32(xp8, wp, a_ph, 0, 0, 0);
      }
    }
  }

  int rr[16];
#pragma unroll
  for (int r = 0; r < 16; ++r) rr[r] = (r & 3) + 8 * (r >> 2) + 4 * hi;

#pragma unroll
  for (int r = 0; r < 16; ++r) {  // theta: rows n, cols o (contig in lo)
    size_t row = ((size_t)b * N_ + n0 + 32 * w + rr[r]) * 64;
    th[row + lo] = f2b(a_th0[r] + LOG2E * bth[lo]);
    th[row + 32 + lo] = f2b(a_th1[r] + LOG2E * bth[32 + lo]);
  }
#pragma unroll
  for (int r = 0; r < 16; ++r) {  // g -> vt[cg][m] (contig in lo along m)
    int cg0 = 64 * w + rr[r];
    vt[((size_t)b * 256 + cg0) * M_ + m0 + lo] = f2b(a_g0[r] + bg[cg0]);
    vt[((size_t)b * 256 + cg0 + 32) * M_ + m0 + lo] = f2b(a_g1[r] + bg[cg0 + 32]);
  }
  if (w < 2) {
#pragma unroll
    for (int r = 0; r < 16; ++r) {  // phi: rows m, cols o
      size_t row = ((size_t)b * M_ + m0 + rr[r]) * 64;
      ph[row + 32 * w + lo] = f2b(a_ph[r] + bph[32 * w + lo]);
    }
  }
}

// ---------------- fused attention + out-conv + residual ----------------
// grid (32, 16): 128 q/block, 4 waves x 32 q, m-chunks of 64, counted-wait dbuf.
__global__ __launch_bounds__(256, 2) void attn_kernel(const u16* __restrict__ th,
                                                      const u16* __restrict__ ph,
                                                      const u16* __restrict__ vt,
                                                      const u16* __restrict__ wo,
                                                      const float* __restrict__ b_out,
                                                      const float* __restrict__ gamma,
                                                      const float* __restrict__ x,
                                                      float* __restrict__ out) {
  __shared__ u16 smem[32768];  // 64KB: Vs[2][32 rows][512] ; epilogue Os[128][256]

  const int t = threadIdx.x;
  const int w = t >> 6, l = t & 63, lo = l & 31, hi = l >> 5;
  const int b = blockIdx.y, n0 = blockIdx.x * 128, qw = n0 + 32 * w;

  int rr[16];
#pragma unroll
  for (int r = 0; r < 16; ++r) rr[r] = (r & 3) + 8 * (r >> 2) + 4 * hi;

  bf16x8 thB[4];  // theta B-frags (col=q=lo, k=c) — log2e-scaled
  {
    const u16* tp = th + ((size_t)(b * N_ + qw + lo) * 64 + 8 * hi);
#pragma unroll
    for (int kh = 0; kh < 4; ++kh) thB[kh] = *(const bf16x8*)(tp + kh * 16);
  }

  f32x16 acc[8];
#pragma unroll
  for (int ct = 0; ct < 8; ++ct) acc[ct] = fz16();
  float m_run = 0.0f, l_run = 0.0f;

  const int srow = l >> 3, sswz = (l & 7) ^ srow;  // LDS linear; source pre-swizzled
  auto stage = [&](int buf, int mc) {
    const u16* gb = vt + ((size_t)(b * 256 + w * 64 + srow) * M_ + mc + sswz * 8);
#pragma unroll
    for (int i = 0; i < 8; ++i)
      async_cp16(&smem[buf * 16384 + (w * 8 + i) * 512], gb + (size_t)i * 8 * M_);
  };

  stage(0, 0);

  for (int ic = 0; ic < 16; ++ic) {
    const int mc = ic * 64, cur = ic & 1;

    // QK^T swapped (S^T tiles; m lane-spread, q=lo). phi vmcnt wait also
    // retires last iter's stage (in-order vmcnt) — this wave's guarantee for BAR1.
    f32x16 S0 = fz16(), S1 = fz16();
    const u16* pp = ph + ((size_t)(b * M_ + mc + lo) * 64 + 8 * hi);
#pragma unroll
    for (int kh = 0; kh < 4; ++kh) {
      bf16x8 p0 = *(const bf16x8*)(pp + kh * 16);
      bf16x8 p1 = *(const bf16x8*)(pp + 32 * 64 + kh * 16);
      S0 = MFMA32(p0, thB[kh], S0, 0, 0, 0);
      S1 = MFMA32(p1, thB[kh], S1, 0, 0, 0);
    }

    __builtin_amdgcn_sched_barrier(0);  // keep stage AFTER phi loads (counted wait)
    if (ic < 15) stage(cur ^ 1, mc + 64);

    // online softmax, exp2 domain; tree reductions
    float mp[16];
#pragma unroll
    for (int i = 0; i < 16; ++i) mp[i] = fmaxf(S0[i], S1[i]);
#pragma unroll
    for (int s = 8; s; s >>= 1)
#pragma unroll
      for (int i = 0; i < s; ++i) mp[i] = fmaxf(mp[i], mp[i + s]);
    float mx = fmaxf(mp[0], __shfl_xor(mp[0], 32, 64));

    if (__any(mx > m_run + 11.0f)) {  // defer-max (T13, log2 units)
      float nm = fmaxf(m_run, mx);
      float sc = exp2v(m_run - nm);
      m_run = nm;
      l_run *= sc;
#pragma unroll
      for (int r = 0; r < 16; ++r) {
        float scr = __shfl(sc, rr[r], 64);
#pragma unroll
        for (int ct = 0; ct < 8; ++ct) acc[ct][r] *= scr;
      }
    }

    float sp[16];
#pragma unroll
    for (int i = 0; i < 16; ++i) {
      S0[i] = exp2v(S0[i] - m_run);
      S1[i] = exp2v(S1[i] - m_run);
      sp[i] = S0[i] + S1[i];
    }
#pragma unroll
    for (int s = 8; s; s >>= 1)
#pragma unroll
      for (int i = 0; i < s; ++i) sp[i] += sp[i + s];
    l_run += sp[0] + __shfl_xor(sp[0], 32, 64);

    // P -> bf16 A-frags in-register (cvt_pk + permlane32_swap, T12)
    bf16x8 Pf[4];
#pragma unroll
    for (int mt = 0; mt < 2; ++mt) {
#pragma unroll
      for (int s = 0; s < 2; ++s) {
        const f32x16& S = mt ? S1 : S0;
        unsigned a0 = cvtpk(S[8 * s + 0], S[8 * s + 1]);
        unsigned a1 = cvtpk(S[8 * s + 2], S[8 * s + 3]);
        unsigned a2 = cvtpk(S[8 * s + 4], S[8 * s + 5]);
        unsigned a3 = cvtpk(S[8 * s + 6], S[8 * s + 7]);
        permswap(a0, a2);
        permswap(a1, a3);
        i32x4 wv = {(int)a0, (int)a1, (int)a2, (int)a3};
        Pf[mt * 2 + s] = __builtin_bit_cast(bf16x8, wv);
      }
    }

    barrier_raw();  // BAR1: all waves passed their QK wait => cur buffer complete

    __builtin_amdgcn_s_setprio(1);
    const u16* vbase = &smem[cur * 16384];
#pragma unroll
    for (int ct = 0; ct < 8; ++ct) {
      bf16x8 vf[4];
#pragma unroll
      for (int kh = 0; kh < 4; ++kh) {
        int blk = (2 * kh + hi) ^ (lo & 7);
        vf[kh] = *(const bf16x8*)(vbase + (32 * ct + lo) * 64 + blk * 8);
      }
#pragma unroll
      for (int kh = 0; kh < 4; ++kh)
        acc[ct] = MFMA32(Pf[kh], vf[kh], acc[ct], 0, 0, 0);
    }
    __builtin_amdgcn_s_setprio(0);

    barrier_raw();  // BAR2: PV reads done before next stage overwrites
  }

  float linv = 1.0f / l_run;
  float linv_r[16];
#pragma unroll
  for (int r = 0; r < 16; ++r) linv_r[r] = __shfl(linv, rr[r], 64);

  // write normalized O tile [128 q][256 cg] bf16, XOR-swizzled rows (wave-own region)
#pragma unroll
  for (int ct = 0; ct < 8; ++ct)
#pragma unroll
    for (int r = 0; r < 16; ++r) {
      int q = 32 * w + rr[r];
      int blk = (4 * ct + (lo >> 3)) ^ (rr[r] & 7);
      smem[q * 256 + blk * 8 + (lo & 7)] = f2b(acc[ct][r] * linv_r[r]);
    }

  bf16x8 Bf[16];
#pragma unroll
  for (int kh = 0; kh < 16; ++kh) {
    int blk = (2 * kh + hi) ^ (lo & 7);
    Bf[kh] = *(const bf16x8*)(&smem[(32 * w + lo) * 256 + blk * 8]);
  }

  const float gamma0 = gamma[0];
#pragma unroll 2
  for (int ct = 0; ct < 16; ++ct) {
    f32x16 facc = fz16();
    const u16* wp = wo + (size_t)(32 * ct + lo) * 256 + 8 * hi;
#pragma unroll
    for (int kh = 0; kh < 16; ++kh) {
      bf16x8 af = *(const bf16x8*)(wp + kh * 16);
      facc = MFMA32(af, Bf[kh], facc, 0, 0, 0);
    }
#pragma unroll
    for (int r = 0; r < 16; ++r) {
      int c = 32 * ct + rr[r];
      size_t idx = ((size_t)(b * C_ + c)) * N_ + n0 + 32 * w + lo;
      out[idx] = gamma0 * (facc[r] + b_out[c]) + x[idx];
    }
  }
}

extern "C" void kernel_launch(void* const* d_in, const int* in_sizes, int n_in,
                              void* d_out, int out_size, void* d_ws, size_t ws_size,
                              hipStream_t stream) {
  (void)in_sizes; (void)n_in; (void)out_size; (void)ws_size;
  const float* x       = (const float*)d_in[0];
  const float* w_theta = (const float*)d_in[1];
  const float* b_theta = (const float*)d_in[2];
  const float* w_phi   = (const float*)d_in[3];
  const float* b_phi   = (const float*)d_in[4];
  const float* w_g     = (const float*)d_in[5];
  const float* b_g     = (const float*)d_in[6];
  const float* w_out   = (const float*)d_in[7];
  const float* b_out   = (const float*)d_in[8];
  const float* gamma   = (const float*)d_in[9];
  float* out = (float*)d_out;

  char* ws = (char*)d_ws;
  u16* th  = (u16*)(ws);               // 16*4096*64*2  = 8,388,608
  u16* ph  = (u16*)(ws + 8388608);     // 16*1024*64*2  = 2,097,152
  u16* vt  = (u16*)(ws + 10485760);    // 16*256*1024*2 = 8,388,608
  u16* wth = (u16*)(ws + 18874368);    // 65,536
  u16* wph = (u16*)(ws + 18939904);    // 65,536
  u16* wg  = (u16*)(ws + 19005440);    // 262,144
  u16* wo  = (u16*)(ws + 19267584);    // 262,144 (end 19,529,728)

  cvt_kernel<<<32, 256, 0, stream>>>(w_theta, wth, 8192, LOG2E);  // exp2 domain
  cvt_kernel<<<32, 256, 0, stream>>>(w_phi, wph, 8192, 1.0f);
  cvt_kernel<<<128, 256, 0, stream>>>(w_g, wg, 32768, 1.0f);
  cvt_kernel<<<128, 256, 0, stream>>>(w_out, wo, 32768, 1.0f);

  prep_kernel<<<dim3(32, 16), 256, 0, stream>>>(x, wth, wph, wg, b_theta, b_phi,
                                                b_g, th, ph, vt);
  attn_kernel<<<dim3(32, 16), 256, 0, stream>>>(th, ph, vt, wo, b_out, gamma, x, out);
}